// Round 29
// baseline (337.351 us; speedup 1.0000x reference)
//
#include <hip/hip_runtime.h>

// Problem constants
#define BDIM   16
#define PDIM   12
#define TDIM   4096
#define WINW   41
#define PADW   20
#define DDIM   492      // P*WIN
#define KCODES 1024

// MX-scaled fp8 MFMA, 32x32x64 (scales=1.0 -> plain fp8). R26/R28 (16x16x128,
// 59us) was bound by 8192 ds_read_b128/CU (~41us LDS throughput). 32x32x64
// gives 32 rows/wave with ONE A-slab -> 8 waves x 512 reads = 4096/CU
// (20.5us floor); MFMA count/CU unchanged. Live ~114 regs = R14's verified
// no-spill config at the 512-thr 128 cap (single A-array, single acc, single
// B temp -- avoids R27's tuple-pair copies that spilled).
#define KCHUNK   8                   // K=64 chunks covering 512
#define TILE_BYTES (KCHUNK * 2 * 64 * 16)   // 16 KiB per 32-code tile

#define WAVES    8                   // 512-thread blocks
#define ROWS_WAVE 32
#define BMROWS   (WAVES * ROWS_WAVE) // 256 rows per block
#define MROWS    (BDIM * TDIM)       // 65536
#define NBLK     (MROWS / BMROWS)    // 256 = 1 block/CU, single round
#define NQ       4                   // codebook quarters
#define QTILES   8                   // 32-code tiles per quarter
#define QBYTES   (QTILES * TILE_BYTES)   // 128 KiB

#define SCALE1   0x7F7F7F7F          // 4x e8m0(127) = 1.0 per 32-elem block

typedef __attribute__((ext_vector_type(16))) float f32x16;
typedef __attribute__((ext_vector_type(2))) long  long2v;
typedef __attribute__((ext_vector_type(4))) int   int4v;
typedef __attribute__((ext_vector_type(8))) int   int8v;

// two f32 pairs -> 4 e4m3 bytes (RNE, saturating) via v_cvt_pk_fp8_f32
__device__ __forceinline__ unsigned int pack4_fp8(float a, float b, float c, float d) {
    int v = 0;
    v = __builtin_amdgcn_cvt_pk_fp8_f32(a, b, v, false);  // bytes 0,1
    v = __builtin_amdgcn_cvt_pk_fp8_f32(c, d, v, true);   // bytes 2,3
    return (unsigned int)v;
}

__device__ __forceinline__ long pack8_fp8(const float* v) {
    unsigned int lo = pack4_fp8(v[0], v[1], v[2], v[3]);
    unsigned int hi = pack4_fp8(v[4], v[5], v[6], v[7]);
    return (long)(((unsigned long long)hi << 32) | lo);
}

// Pre-format codebook into fp8 B-fragments for mfma_scale_f32_32x32x64.
// Entry e = ((nt*KCHUNK + kc)*2 + half)*64 + lane holds 16 bytes:
//   B[k][n], n = nt*32 + (lane&31), k = kc*64 + (lane>>5)*32 + half*16 + jj
//   (jj = 0..15). Tile offset = kc*2048 + half*1024 + lane*16 -> both b128
//   reads per MFMA are 16B-stride (bank-conflict-free). Mirrors the A-build
//   k-mapping exactly (k-permutation symmetry).
__global__ __launch_bounds__(256) void prep_bfrag_k(const float* __restrict__ cb,
                                                    long2v* __restrict__ bfrag) {
    int e    = blockIdx.x * 256 + threadIdx.x;   // 0..32767
    int lane = e & 63;
    int half = (e >> 6) & 1;
    int kc   = (e >> 7) & (KCHUNK - 1);
    int nt   = e >> 10;                          // 0..31
    int n    = nt * 32 + (lane & 31);
    int k0   = kc * 64 + (lane >> 5) * 32 + half * 16;
    float v0[8], v1[8];
#pragma unroll
    for (int j = 0; j < 8; ++j) {
        int ka = k0 + j;
        int kb = k0 + 8 + j;
        v0[j] = (ka < DDIM) ? cb[n * DDIM + ka] : 0.f;
        v1[j] = (kb < DDIM) ? cb[n * DDIM + kb] : 0.f;
    }
    long2v out;
    out[0] = pack8_fp8(v0);
    out[1] = pack8_fp8(v1);
    bfrag[e] = out;
}

// Exact fp32 code norms.
__global__ __launch_bounds__(64) void prep_cnorm_k(const float* __restrict__ cb,
                                                   float* __restrict__ cnorm) {
    int n = blockIdx.x;
    int lane = threadIdx.x;
    float s = 0.f;
    for (int d = lane; d < DDIM; d += 64) { float c = cb[n * DDIM + d]; s += c * c; }
#pragma unroll
    for (int m = 1; m < 64; m <<= 1) s += __shfl_xor(s, m, 64);
    if (lane == 0) cnorm[n] = s;
}

// Exact sum of ||f||^2 over all rows via window multiplicity:
// mult(tt) = 41 - max(0,20-tt) - max(0,tt-4075).
__global__ __launch_bounds__(256) void xsq_k(const float* __restrict__ x,
                                             float* __restrict__ xsq_part) {
    float s = 0.f;
    for (int i = blockIdx.x * 256 + threadIdx.x; i < BDIM * PDIM * TDIM; i += 256 * 256) {
        int tt = i & (TDIM - 1);
        int mult = WINW - max(0, PADW - tt) - max(0, tt - (TDIM - 1 - PADW));
        float v = x[i];
        s += (float)mult * v * v;
    }
#pragma unroll
    for (int m = 1; m < 64; m <<= 1) s += __shfl_xor(s, m, 64);
    __shared__ float sm[4];
    if ((threadIdx.x & 63) == 0) sm[threadIdx.x >> 6] = s;
    __syncthreads();
    if (threadIdx.x == 0) xsq_part[blockIdx.x] = sm[0] + sm[1] + sm[2] + sm[3];
}

// Stage one 128 KiB quarter into LDS: 512 thr x 16 B = 8 KiB per round,
// 16 rounds -> 16 global_load_lds per thread.
__device__ __forceinline__ void stage_quarter(const unsigned char* __restrict__ gq,
                                              unsigned char* smem, int wave, int lane) {
#pragma unroll
    for (int i = 0; i < 16; ++i) {
        int off = i * 8192 + wave * 1024;
        __builtin_amdgcn_global_load_lds(
            (const __attribute__((address_space(1))) unsigned int*)(gq + off + lane * 16),
            (__attribute__((address_space(3))) unsigned int*)(smem + off),
            16, 0, 0);
    }
}

// windowed-x fetch: element d of row with time-index t
__device__ __forceinline__ float fetchx(const float* __restrict__ xb, int t, int d) {
    if (d >= DDIM) return 0.f;
    int p  = d / WINW;
    int w  = d - p * WINW;
    int tt = t + w - PADW;
    return (tt >= 0 && tt < TDIM) ? xb[p * TDIM + tt] : 0.f;
}

// Main sweep: 256 blocks (1/CU) x 8 waves x 32 rows, single round.
// Prologue: stage quarter 0 + sb table + A-build + one sync. Then 4x
// { barrier-free sweep (8 tiles x 8 MX-MFMAs x 16 b128 reads, zero sync
// inside); sync; restage; sync }.
__global__ __launch_bounds__(512)
void vq_main_k(const float* __restrict__ x,
               const unsigned char* __restrict__ bfrag,
               const float* __restrict__ cnorm,
               float* __restrict__ bpart) {
    __shared__ __align__(16) unsigned char smem[QBYTES];   // 128 KiB
    __shared__ float sb_lds[KCODES];                       // 4 KiB
    __shared__ float gsum[2 * WAVES];

    const int lane = threadIdx.x & 63;
    const int wave = threadIdx.x >> 6;
    const int col  = lane & 31;     // B/D column within 32-code tile
    const int hi2  = lane >> 5;
    const int rowbase = blockIdx.x * BMROWS + wave * ROWS_WAVE;

    // Stage quarter 0; latency covered by sb-table + A-build below.
    stage_quarter(bfrag, smem, wave, lane);

    // Full bias table: sb_lds[n] = -0.5*||c_n||^2
    for (int i = threadIdx.x; i < KCODES; i += 512)
        sb_lds[i] = -0.5f * cnorm[i];

    // ---- fp8 A-build: row = rowbase + col, k = kc*64 + hi2*32 + 4m + b
    //      (mirrors prep's B k-mapping). sched_barrier per kc bounds peak. ----
    int8v afr[KCHUNK];
    {
        int row = rowbase + col;
        int t = row & (TDIM - 1);
        const float* xb = x + (size_t)(row >> 12) * (PDIM * TDIM);
#pragma unroll
        for (int kc = 0; kc < KCHUNK; ++kc) {
#pragma unroll
            for (int m = 0; m < 8; ++m) {
                int d = kc * 64 + hi2 * 32 + m * 4;
                float f0 = fetchx(xb, t, d + 0);
                float f1 = fetchx(xb, t, d + 1);
                float f2 = fetchx(xb, t, d + 2);
                float f3 = fetchx(xb, t, d + 3);
                afr[kc][m] = (int)pack4_fp8(f0, f1, f2, f3);
            }
            __builtin_amdgcn_sched_barrier(0);   // bound prologue pressure
        }
    }

    f32x16 bs;
#pragma unroll
    for (int r = 0; r < 16; ++r) bs[r] = -3.0e38f;

    // Entry drain: quarter 0 resident; sb_lds visible.
    __syncthreads();

    for (int q = 0; q < NQ; ++q) {
        // ---- Barrier-free sweep of the resident quarter ----
        for (int tl = 0; tl < QTILES; ++tl) {
            const unsigned char* tb = smem + tl * TILE_BYTES;
            f32x16 acc;
#pragma unroll
            for (int r = 0; r < 16; ++r) acc[r] = 0.f;
#pragma unroll
            for (int kc = 0; kc < KCHUNK; ++kc) {
                int8v b;
                *(int4v*)&b         = *(const int4v*)(tb + kc * 2048 + lane * 16);
                *(((int4v*)&b) + 1) = *(const int4v*)(tb + kc * 2048 + 1024 + lane * 16);
                acc = __builtin_amdgcn_mfma_scale_f32_32x32x64_f8f6f4(
                          afr[kc], b, acc, 0, 0, 0, SCALE1, 0, SCALE1);
            }
            const float sb = sb_lds[q * (KCODES / NQ) + tl * 32 + col];
#pragma unroll
            for (int r = 0; r < 16; ++r)
                bs[r] = fmaxf(bs[r], acc[r] + sb);
        }
        // ---- Restage next quarter (2 barriers per transition) ----
        if (q + 1 < NQ) {
            __syncthreads();   // all waves done reading smem
            stage_quarter(bfrag + (size_t)(q + 1) * QBYTES, smem, wave, lane);
            __syncthreads();   // drains vmcnt(0): next quarter resident
        }
    }

    // ---- Per-row max across the 32 col-lanes (masks<32 preserve hi2) ----
#pragma unroll
    for (int m = 1; m < 32; m <<= 1)
#pragma unroll
        for (int r = 0; r < 16; ++r)
            bs[r] = fmaxf(bs[r], __shfl_xor(bs[r], m, 64));

    // D rows: row = (r&3) + 8*(r>>2) + 4*hi2 — bijective over the 32-row
    // slab; sum over all rows is mapping-invariant.
    if (col == 0) {
        float s = 0.f;
#pragma unroll
        for (int r = 0; r < 16; ++r) s += bs[r];
        gsum[wave * 2 + hi2] = s;
    }
    __syncthreads();
    if (threadIdx.x == 0) {
        float tot = 0.f;
#pragma unroll
        for (int i = 0; i < 2 * WAVES; ++i) tot += gsum[i];
        bpart[blockIdx.x] = tot;
    }
}

// loss = 0.25 * (Sxx - 2*sum_blocks bpart) / (65536*492)
__global__ __launch_bounds__(256) void finalize_k(const float* __restrict__ bpart,
                                                  const float* __restrict__ xsq_part,
                                                  float* __restrict__ out) {
    __shared__ double sm[256];
    int tid = threadIdx.x;
    sm[tid] = (double)bpart[tid];
    __syncthreads();
    for (int st = 128; st > 0; st >>= 1) {
        if (tid < st) sm[tid] += sm[tid + st];
        __syncthreads();
    }
    double S1 = sm[0];
    __syncthreads();
    sm[tid] = (double)xsq_part[tid];
    __syncthreads();
    for (int st = 128; st > 0; st >>= 1) {
        if (tid < st) sm[tid] += sm[tid + st];
        __syncthreads();
    }
    if (tid == 0)
        out[0] = (float)(0.25 * (sm[0] - 2.0 * S1) / ((double)MROWS * (double)DDIM));
}

extern "C" void kernel_launch(void* const* d_in, const int* in_sizes, int n_in,
                              void* d_out, int out_size, void* d_ws, size_t ws_size,
                              hipStream_t stream) {
    const float* x  = (const float*)d_in[0];   // (16,12,4096) f32
    const float* cb = (const float*)d_in[1];   // (1024,492) f32
    float* out = (float*)d_out;

    // workspace layout (~524 KiB)
    char* ws = (char*)d_ws;
    long2v* bfrag   = (long2v*)ws;                                  // 512 KiB
    float* cnorm    = (float*)(ws + (512u << 10));                  // 4 KiB
    float* xsq_part = (float*)(ws + (512u << 10) + 4096);           // 1 KiB
    float* bpart    = (float*)(ws + (512u << 10) + 8192);           // 1 KiB

    prep_bfrag_k<<<128, 256, 0, stream>>>(cb, bfrag);
    prep_cnorm_k<<<KCODES, 64, 0, stream>>>(cb, cnorm);
    xsq_k<<<256, 256, 0, stream>>>(x, xsq_part);
    vq_main_k<<<NBLK, 512, 0, stream>>>(x, (const unsigned char*)bfrag, cnorm, bpart);
    finalize_k<<<1, 256, 0, stream>>>(bpart, xsq_part, out);
}

// Round 30
// 61.791 us; speedup vs baseline: 5.4595x; 5.4595x over previous
//
#include <hip/hip_runtime.h>

// Problem constants
#define BDIM   16
#define PDIM   12
#define TDIM   4096
#define WINW   41
#define PADW   20
#define DDIM   492      // P*WIN
#define KCODES 1024

// R30: B codebook in MXFP4 (e2m1 + per-32-block e8m0 scales), A in fp8
// (scale 1.0), via mfma_scale_f32_16x16x128_f8f6f4 with cbsz=0 (fp8 A),
// blgp=4 (fp4 B). R26 (all-fp8, 59us) was bound by 8192 ds_read_b128/CU
// (~41us LDS throughput); fp4 B halves the B bytes -> 1 b128 per MFMA
// (+1 scale b128 per tile) = 5120 reads/CU (~26us floor). Reuse-doubling
// alternatives all spilled (R21/R27/R29: scale-MFMA tuple copies).
#define KCHUNK   4                   // K=128 chunks covering 512
#define TILEB    4096                // 4 kc x 64 lanes x 16 B fp4 per 16-code tile
#define NTILES   64

#define WAVES    16                  // 1024-thread blocks (4 waves/SIMD)
#define ROWS_WAVE 16
#define BMROWS   (WAVES * ROWS_WAVE) // 256 rows per block
#define MROWS    (BDIM * TDIM)       // 65536
#define NBLK     (MROWS / BMROWS)    // 256 = 1 block/CU, single round
#define NQ       4                   // codebook quarters (B restaged)
#define QTILES   16
#define QBYTES   (QTILES * TILEB)    // 64 KiB per B quarter
#define SBYTES   (NTILES * 1024)     // 64 KiB scale table (all tiles, resident)

#define SCALE1   0x7F7F7F7F          // e8m0 127 = 1.0 (A side)

typedef __attribute__((ext_vector_type(4))) float f32x4;
typedef __attribute__((ext_vector_type(4))) int   int4v;
typedef __attribute__((ext_vector_type(8))) int   int8v;

// two f32 pairs -> 4 e4m3 bytes (RNE, saturating) via v_cvt_pk_fp8_f32
__device__ __forceinline__ unsigned int pack4_fp8(float a, float b, float c, float d) {
    int v = 0;
    v = __builtin_amdgcn_cvt_pk_fp8_f32(a, b, v, false);  // bytes 0,1
    v = __builtin_amdgcn_cvt_pk_fp8_f32(c, d, v, true);   // bytes 2,3
    return (unsigned int)v;
}

// e2m1 encode of u (already divided by block scale): nearest of
// {0,.5,1,1.5,2,3,4,6}, sign in bit 3.
__device__ __forceinline__ unsigned enc_fp4(float u) {
    unsigned s = (u < 0.f) ? 8u : 0u;
    float a = fabsf(u);
    unsigned c;
    if      (a < 0.25f) c = 0;
    else if (a < 0.75f) c = 1;
    else if (a < 1.25f) c = 2;
    else if (a < 1.75f) c = 3;
    else if (a < 2.5f)  c = 4;
    else if (a < 3.5f)  c = 5;
    else if (a < 5.0f)  c = 6;
    else                c = 7;
    return s | c;
}

// Pre-format codebook into MXFP4 B-fragments + e8m0 scale table.
// Entry e = (nt*KCHUNK + kc)*64 + lane (16384 entries, 16 B each):
//   B[k][n] fp4, n = nt*16 + (lane&15), k = kc*128 + (lane>>4)*32 + j,
//   element j in nibble j (little-endian nibbles). Each entry is exactly one
//   32-elem MX block -> one e8m0 scale, written (byte-replicated) to
//   bscale[nt*256 + lane*4 + kc] so the sweep reads a tile's 4 scale words
//   as one b128 at [nt*1024 + lane*16].
__global__ __launch_bounds__(256) void prep_bfp4_k(const float* __restrict__ cb,
                                                   unsigned int* __restrict__ bfp4,
                                                   unsigned int* __restrict__ bscale) {
    int e    = blockIdx.x * 256 + threadIdx.x;   // 0..16383
    int lane = e & 63;
    int kc   = (e >> 6) & (KCHUNK - 1);
    int nt   = e >> 8;
    int n    = nt * 16 + (lane & 15);
    int kbase = kc * 128 + (lane >> 4) * 32;
    float v[32];
    float mx = 0.f;
#pragma unroll
    for (int j = 0; j < 32; ++j) {
        int k = kbase + j;
        float f = (k < DDIM) ? cb[n * DDIM + k] : 0.f;
        v[j] = f;
        mx = fmaxf(mx, fabsf(f));
    }
    int eb; float inv;
    if (mx == 0.f) { eb = 127; inv = 1.f; }
    else {
        int ee = (int)ceilf(log2f(mx * (1.0f / 6.0f)));
        ee = min(127, max(-127, ee));
        eb = ee + 127;
        inv = exp2f((float)(-ee));
    }
    unsigned w[4];
#pragma unroll
    for (int wi = 0; wi < 4; ++wi) {
        unsigned acc = 0;
#pragma unroll
        for (int b = 0; b < 8; ++b)
            acc |= enc_fp4(v[wi * 8 + b] * inv) << (4 * b);
        w[wi] = acc;
    }
    int4v out; out[0] = (int)w[0]; out[1] = (int)w[1]; out[2] = (int)w[2]; out[3] = (int)w[3];
    *(int4v*)(bfp4 + (size_t)e * 4) = out;
    bscale[nt * 256 + lane * 4 + kc] = (unsigned)eb * 0x01010101u;
}

// Exact fp32 code norms.
__global__ __launch_bounds__(64) void prep_cnorm_k(const float* __restrict__ cb,
                                                   float* __restrict__ cnorm) {
    int n = blockIdx.x;
    int lane = threadIdx.x;
    float s = 0.f;
    for (int d = lane; d < DDIM; d += 64) { float c = cb[n * DDIM + d]; s += c * c; }
#pragma unroll
    for (int m = 1; m < 64; m <<= 1) s += __shfl_xor(s, m, 64);
    if (lane == 0) cnorm[n] = s;
}

// Exact sum of ||f||^2 over all rows via window multiplicity:
// mult(tt) = 41 - max(0,20-tt) - max(0,tt-4075).
__global__ __launch_bounds__(256) void xsq_k(const float* __restrict__ x,
                                             float* __restrict__ xsq_part) {
    float s = 0.f;
    for (int i = blockIdx.x * 256 + threadIdx.x; i < BDIM * PDIM * TDIM; i += 256 * 256) {
        int tt = i & (TDIM - 1);
        int mult = WINW - max(0, PADW - tt) - max(0, tt - (TDIM - 1 - PADW));
        float v = x[i];
        s += (float)mult * v * v;
    }
#pragma unroll
    for (int m = 1; m < 64; m <<= 1) s += __shfl_xor(s, m, 64);
    __shared__ float sm[4];
    if ((threadIdx.x & 63) == 0) sm[threadIdx.x >> 6] = s;
    __syncthreads();
    if (threadIdx.x == 0) xsq_part[blockIdx.x] = sm[0] + sm[1] + sm[2] + sm[3];
}

// Stage `rounds` x 16 KiB into LDS (1024 thr x 16 B per round, linear).
__device__ __forceinline__ void stage_lin(const unsigned char* __restrict__ g,
                                          unsigned char* smem, int rounds,
                                          int wave, int lane) {
    for (int i = 0; i < rounds; ++i) {
        int off = i * 16384 + wave * 1024;
        __builtin_amdgcn_global_load_lds(
            (const __attribute__((address_space(1))) unsigned int*)(g + off + lane * 16),
            (__attribute__((address_space(3))) unsigned int*)(smem + off),
            16, 0, 0);
    }
}

// windowed-x fetch: element d of row with time-index t
__device__ __forceinline__ float fetchx(const float* __restrict__ xb, int t, int d) {
    if (d >= DDIM) return 0.f;
    int p  = d / WINW;
    int w  = d - p * WINW;
    int tt = t + w - PADW;
    return (tt >= 0 && tt < TDIM) ? xb[p * TDIM + tt] : 0.f;
}

// Main sweep: 256 blocks (1/CU) x 16 waves x 16 rows, single round.
// Prologue: stage scale table (64 KB, resident) + B quarter 0 (64 KB) + sb
// table + fp8 A-build + one sync. Then 4x { barrier-free sweep (16 tiles x
// {1 scale b128 + 4 x (1 B b128 + 1 MX-MFMA)}); sync; restage B; sync }.
__global__ __launch_bounds__(1024)
void vq_main_k(const float* __restrict__ x,
               const unsigned char* __restrict__ bfp4,
               const unsigned char* __restrict__ bscale,
               const float* __restrict__ cnorm,
               float* __restrict__ bpart) {
    __shared__ __align__(16) unsigned char smemB[QBYTES];   // 64 KiB (B quarter)
    __shared__ __align__(16) unsigned char smemS[SBYTES];   // 64 KiB (all scales)
    __shared__ float sb_lds[KCODES];                        // 4 KiB
    __shared__ float gsum[4 * WAVES];

    const int lane = threadIdx.x & 63;
    const int wave = threadIdx.x >> 6;
    const int col  = lane & 15;     // B/D column within 16-code tile
    const int hi   = lane >> 4;
    const int rowbase = blockIdx.x * BMROWS + wave * ROWS_WAVE;

    // Stage scales (whole table) + B quarter 0; latency covered below.
    stage_lin(bscale, smemS, 4, wave, lane);
    stage_lin(bfp4, smemB, 4, wave, lane);

    // Full bias table: sb_lds[n] = -0.5*||c_n||^2
    for (int i = threadIdx.x; i < KCODES; i += 1024)
        sb_lds[i] = -0.5f * cnorm[i];

    // ---- fp8 A-build: row = rowbase + col, k = kc*128 + hi*32 + 4m + b ----
    int8v afr[KCHUNK];
    {
        int row = rowbase + col;
        int t = row & (TDIM - 1);
        const float* xb = x + (size_t)(row >> 12) * (PDIM * TDIM);
#pragma unroll
        for (int kc = 0; kc < KCHUNK; ++kc) {
#pragma unroll
            for (int m = 0; m < 8; ++m) {
                int d = kc * 128 + hi * 32 + m * 4;
                afr[kc][m] = (int)pack4_fp8(fetchx(xb, t, d + 0), fetchx(xb, t, d + 1),
                                            fetchx(xb, t, d + 2), fetchx(xb, t, d + 3));
            }
            __builtin_amdgcn_sched_barrier(0);   // bound prologue pressure
        }
    }

    float bs[4];
#pragma unroll
    for (int r = 0; r < 4; ++r) bs[r] = -3.0e38f;

    // Entry drain: scales + quarter 0 resident; sb_lds visible.
    __syncthreads();

    for (int q = 0; q < NQ; ++q) {
        // ---- Barrier-free sweep of the resident quarter ----
        for (int tl = 0; tl < QTILES; ++tl) {
            const int gt = q * QTILES + tl;
            const unsigned char* tb = smemB + tl * TILEB;
            int4v scw = *(const int4v*)(smemS + gt * 1024 + lane * 16);
            f32x4 acc = {0.f, 0.f, 0.f, 0.f};
#pragma unroll
            for (int kc = 0; kc < KCHUNK; ++kc) {
                int8v b;
                *(int4v*)&b         = *(const int4v*)(tb + kc * 1024 + lane * 16);
                *(((int4v*)&b) + 1) = *(int4v*)&b;   // upper half unused (blgp=4)
                acc = __builtin_amdgcn_mfma_scale_f32_16x16x128_f8f6f4(
                          afr[kc], b, acc, 0, 4, 0, SCALE1, 0, scw[kc]);
            }
            const float sb = sb_lds[gt * 16 + col];
#pragma unroll
            for (int r = 0; r < 4; ++r)          // D: col=lane&15, row=hi*4+r
                bs[r] = fmaxf(bs[r], acc[r] + sb);
        }
        // ---- Restage next B quarter (2 barriers per transition) ----
        if (q + 1 < NQ) {
            __syncthreads();   // all waves done reading smemB
            stage_lin(bfp4 + (size_t)(q + 1) * QBYTES, smemB, 4, wave, lane);
            __syncthreads();   // drains vmcnt(0): next quarter resident
        }
    }

    // ---- Per-row max across the 16 col-lanes (masks<16 preserve hi) ----
#pragma unroll
    for (int m = 1; m < 16; m <<= 1)
#pragma unroll
        for (int r = 0; r < 4; ++r)
            bs[r] = fmaxf(bs[r], __shfl_xor(bs[r], m, 64));

    // Lane col==0 of each 16-lane group owns rows {hi*4 + r} of the slab.
    if (col == 0) {
        float s = 0.f;
#pragma unroll
        for (int r = 0; r < 4; ++r) s += bs[r];
        gsum[wave * 4 + hi] = s;
    }
    __syncthreads();
    if (threadIdx.x == 0) {
        float tot = 0.f;
#pragma unroll
        for (int i = 0; i < 4 * WAVES; ++i) tot += gsum[i];
        bpart[blockIdx.x] = tot;
    }
}

// loss = 0.25 * (Sxx - 2*sum_blocks bpart) / (65536*492)
__global__ __launch_bounds__(256) void finalize_k(const float* __restrict__ bpart,
                                                  const float* __restrict__ xsq_part,
                                                  float* __restrict__ out) {
    __shared__ double sm[256];
    int tid = threadIdx.x;
    sm[tid] = (double)bpart[tid];
    __syncthreads();
    for (int st = 128; st > 0; st >>= 1) {
        if (tid < st) sm[tid] += sm[tid + st];
        __syncthreads();
    }
    double S1 = sm[0];
    __syncthreads();
    sm[tid] = (double)xsq_part[tid];
    __syncthreads();
    for (int st = 128; st > 0; st >>= 1) {
        if (tid < st) sm[tid] += sm[tid + st];
        __syncthreads();
    }
    if (tid == 0)
        out[0] = (float)(0.25 * (sm[0] - 2.0 * S1) / ((double)MROWS * (double)DDIM));
}

extern "C" void kernel_launch(void* const* d_in, const int* in_sizes, int n_in,
                              void* d_out, int out_size, void* d_ws, size_t ws_size,
                              hipStream_t stream) {
    const float* x  = (const float*)d_in[0];   // (16,12,4096) f32
    const float* cb = (const float*)d_in[1];   // (1024,492) f32
    float* out = (float*)d_out;

    // workspace layout (~326 KiB)
    char* ws = (char*)d_ws;
    unsigned int* bfp4   = (unsigned int*)ws;                       // 256 KiB
    unsigned int* bscale = (unsigned int*)(ws + (256u << 10));      // 64 KiB
    float* cnorm    = (float*)(ws + (320u << 10));                  // 4 KiB
    float* xsq_part = (float*)(ws + (320u << 10) + 4096);           // 1 KiB
    float* bpart    = (float*)(ws + (320u << 10) + 8192);           // 1 KiB

    prep_bfp4_k<<<64, 256, 0, stream>>>(cb, bfp4, bscale);
    prep_cnorm_k<<<KCODES, 64, 0, stream>>>(cb, cnorm);
    xsq_k<<<256, 256, 0, stream>>>(x, xsq_part);
    vq_main_k<<<NBLK, 1024, 0, stream>>>(x, (const unsigned char*)bfp4,
                                         (const unsigned char*)bscale, cnorm, bpart);
    finalize_k<<<1, 256, 0, stream>>>(bpart, xsq_part, out);
}